// Round 9
// baseline (85.294 us; speedup 1.0000x reference)
//
#include <hip/hip_runtime.h>

#define HW   4096      // 64*64
#define NC   256
#define NTB  24        // 3 tensors * 8 batches
#define TOPK 2048      // max(1, int(0.5 * 4096))

typedef float vf4 __attribute__((ext_vector_type(4)));

// ---------------------------------------------------------------------------
// K1 (pass A): imp[tb][hw] = (sum_{c seq} |x|)/256, bitwise == np order.
// R5-proven: scalar chain/thread, 384 blocks x 256, unroll-32. ~3.5 us
// (inputs L3-resident in steady-state replay; R7/R8 probe algebra).
// ---------------------------------------------------------------------------
__global__ __launch_bounds__(256) void k_imp(const float* __restrict__ i0,
                                             const float* __restrict__ i1,
                                             const float* __restrict__ i2,
                                             float* __restrict__ imp) {
  int tid = blockIdx.x * 256 + threadIdx.x;   // 0 .. 98303
  int hw  = tid & (HW - 1);
  int tb  = tid >> 12;                        // 0 .. 23
  int t   = tb >> 3;
  const float* base = (t == 0 ? i0 : (t == 1 ? i1 : i2));
  const float* p = base + (size_t)(tb & 7) * NC * HW + hw;
  float s = 0.f;
#pragma unroll 32
  for (int c = 0; c < NC; ++c) s += fabsf(p[c * HW]);  // program order per chain
  imp[tid] = s * (1.0f / 256.0f);             // exact pow2 == /256.0
}

// ---------------------------------------------------------------------------
// K2 (pass B+C fused): 1536 blocks = 24 rows x 64 chunks (4 channels each).
// Wave 0 of EVERY block redundantly recomputes its row's top-k select
// (exact R5 wave-select math, absmax-0 proven; input = imp row in ws) and
// writes the 4096-wide mask as 128 bit-words into LDS. One __syncthreads,
// then all 256 threads stream 4 channels: cached vf4 loads (L3-resident),
// bit-select (masked-in values bitwise identical; 0.0 vs -0.0 -> absmax 0),
// nontemporal stores (protect input L3 residency for next replay's K1).
// All 64 blocks of a row compute identical select from identical imp data
// -> deterministic. No grid sync, no atomics, mask never touches global.
// ---------------------------------------------------------------------------
#define CH_PER_BLK   4
#define BLKS_PER_ROW (NC / CH_PER_BLK)        // 64
#define K2_BLOCKS    (NTB * BLKS_PER_ROW)     // 1536
#define VF4_PER_BLK  (CH_PER_BLK * HW / 4)    // 4096
#define VF4_PER_THR  (VF4_PER_BLK / 256)      // 16

__global__ __launch_bounds__(256) void k_maskapply(const float* __restrict__ i0,
                                                   const float* __restrict__ i1,
                                                   const float* __restrict__ i2,
                                                   const float* __restrict__ imp,
                                                   vf4* __restrict__ out) {
  __shared__ unsigned mbits[HW / 32];          // 128 words = full row mask
  const int blk = blockIdx.x;
  const int row = blk >> 6;                    // 0..23 (t*8+b)
  const int cb  = blk & 63;                    // channel-chunk within row
  const int tid = threadIdx.x;

  if (tid < 64) {                              // wave 0: row select (R5 math)
    const int lane = tid;
    const float* base = imp + (size_t)row * HW;
    unsigned u[64];
    const vf4* p = reinterpret_cast<const vf4*>(base + lane * 64);
#pragma unroll
    for (int j = 0; j < 16; ++j) {
      vf4 v = p[j];
      u[4 * j + 0] = __float_as_uint(v.x);
      u[4 * j + 1] = __float_as_uint(v.y);
      u[4 * j + 2] = __float_as_uint(v.z);
      u[4 * j + 3] = __float_as_uint(v.w);
    }
    unsigned mx = 0u, mn = 0xFFFFFFFFu;
#pragma unroll
    for (int j = 0; j < 64; ++j) {
      mx = (u[j] > mx) ? u[j] : mx;
      mn = (u[j] < mn) ? u[j] : mn;
    }
#pragma unroll
    for (int off = 32; off > 0; off >>= 1) {
      unsigned ox = (unsigned)__shfl_xor((int)mx, off, 64);
      unsigned on = (unsigned)__shfl_xor((int)mn, off, 64);
      mx = (ox > mx) ? ox : mx;
      mn = (on < mn) ? on : mn;
    }
    unsigned lo = mn, hi = mx + 1u;            // cnt_ge(lo)>=K, cnt_ge(hi)<K
    while (hi - lo > 1u) {
      unsigned mid = lo + ((hi - lo) >> 1);
      int c = 0;
#pragma unroll
      for (int j = 0; j < 64; ++j) c += (u[j] >= mid);
#pragma unroll
      for (int off = 32; off > 0; off >>= 1) c += __shfl_xor(c, off, 64);
      if (c >= TOPK) lo = mid; else hi = mid;  // c uniform across lanes
    }
    const unsigned thr = lo;
    int eq = 0, gt = 0;
#pragma unroll
    for (int j = 0; j < 64; ++j) {
      eq += (u[j] == thr);
      gt += (u[j] > thr);
    }
    int g_tot = gt;
#pragma unroll
    for (int off = 32; off > 0; off >>= 1) g_tot += __shfl_xor(g_tot, off, 64);
    int incl = eq;
#pragma unroll
    for (int off = 1; off < 64; off <<= 1) {
      int n = __shfl_up(incl, off, 64);
      if (lane >= off) incl += n;
    }
    int r = incl - eq;                         // starting tie-rank, lane order
    const int needed = TOPK - g_tot;           // >=1 by search invariant
    unsigned w0 = 0u, w1 = 0u;
#pragma unroll
    for (int j = 0; j < 64; ++j) {             // same keep-decision as R5
      unsigned x = u[j];
      int e = (x == thr);
      unsigned keep = (x > thr || (e && r < needed)) ? 1u : 0u;
      if (j < 32) w0 |= keep << j; else w1 |= keep << (j - 32);
      r += e;
    }
    mbits[2 * lane]     = w0;                  // hw [lane*64,    lane*64+32)
    mbits[2 * lane + 1] = w1;                  // hw [lane*64+32, lane*64+64)
  }
  __syncthreads();

  // apply: 4 channels of this row, 16 vf4/thread in 4 batches of 4
  const int t = row >> 3;
  const vf4* src = (t == 0 ? (const vf4*)i0 : (t == 1 ? (const vf4*)i1 : (const vf4*)i2));
  const size_t src_base = ((size_t)(row & 7) * NC + (size_t)cb * CH_PER_BLK) * (HW / 4);
  vf4* obase = out + (size_t)row * NC * (HW / 4) + (size_t)cb * CH_PER_BLK * (HW / 4);
#pragma unroll
  for (int it = 0; it < VF4_PER_THR / 4; ++it) {
    int jj[4];
    vf4 a[4];
    unsigned nib[4];
#pragma unroll
    for (int q = 0; q < 4; ++q) {
      int j = tid + (it * 4 + q) * 256;        // 0..4095 vf4 within chunk
      jj[q] = j;
      a[q] = src[src_base + j];                // cached read (L3-resident)
      int h4 = j & 1023;                       // hw4 (chunk is channel-aligned)
      nib[q] = (mbits[h4 >> 3] >> ((h4 & 7) * 4)) & 15u;
    }
#pragma unroll
    for (int q = 0; q < 4; ++q) {
      vf4 r;
      r.x = (nib[q] & 1u) ? a[q].x : 0.f;
      r.y = (nib[q] & 2u) ? a[q].y : 0.f;
      r.z = (nib[q] & 4u) ? a[q].z : 0.f;
      r.w = (nib[q] & 8u) ? a[q].w : 0.f;
      __builtin_nontemporal_store(r, &obase[jj[q]]);
    }
  }
}

extern "C" void kernel_launch(void* const* d_in, const int* in_sizes, int n_in,
                              void* d_out, int out_size, void* d_ws, size_t ws_size,
                              hipStream_t stream) {
  const float* i0 = (const float*)d_in[0];
  const float* i1 = (const float*)d_in[1];
  const float* i2 = (const float*)d_in[2];
  float* imp = (float*)d_ws;   // 384 KB scratch (imp only; mask stays on-chip)

  k_imp<<<384, 256, 0, stream>>>(i0, i1, i2, imp);
  k_maskapply<<<K2_BLOCKS, 256, 0, stream>>>(i0, i1, i2, imp, (vf4*)d_out);
}

// Round 10
// 71.232 us; speedup vs baseline: 1.1974x; 1.1974x over previous
//
#include <hip/hip_runtime.h>

#define HW   4096      // 64*64
#define NC   256
#define NTB  24        // 3 tensors * 8 batches
#define TOPK 2048      // max(1, int(0.5 * 4096))

typedef float vf4 __attribute__((ext_vector_type(4)));

// ---------------------------------------------------------------------------
// K1 (pass A): imp[tb][hw] = (sum_{c seq} |x|)/256, bitwise == np order.
// R5-proven: scalar chain/thread, 384 blocks x 256, unroll-32. ~3.5 us
// (inputs L3-resident in steady-state replay; R7/R8 probe algebra).
// ---------------------------------------------------------------------------
__global__ __launch_bounds__(256) void k_imp(const float* __restrict__ i0,
                                             const float* __restrict__ i1,
                                             const float* __restrict__ i2,
                                             float* __restrict__ imp) {
  int tid = blockIdx.x * 256 + threadIdx.x;   // 0 .. 98303
  int hw  = tid & (HW - 1);
  int tb  = tid >> 12;                        // 0 .. 23
  int t   = tb >> 3;
  const float* base = (t == 0 ? i0 : (t == 1 ? i1 : i2));
  const float* p = base + (size_t)(tb & 7) * NC * HW + hw;
  float s = 0.f;
#pragma unroll 32
  for (int c = 0; c < NC; ++c) s += fabsf(p[c * HW]);  // program order per chain
  imp[tid] = s * (1.0f / 256.0f);             // exact pow2 == /256.0
}

// ---------------------------------------------------------------------------
// K2 (select+apply fused): 1536 blocks x 64 THREADS (one wave), so the R5
// select's u[64] stays in REGISTERS (R9's 256-thr version spilled: VGPR=56 <
// 64 needed -> scratch thrash, 66 us). Each wave redundantly recomputes its
// row's top-k threshold+mask (exact R5 math, absmax-0 proven), deposits the
// 4096-bit mask in 128 LDS words, then streams its 4-channel chunk:
// 64 vf4/thread, 8 batches of 8 in-flight (49 KB/CU read ILP at 6 waves/CU),
// cached loads (L3-resident), bit-select, nontemporal stores.
// Redundancy cost ~4-5 us chip-wide < +9.5 us for a third dispatch.
// ---------------------------------------------------------------------------
#define CH_PER_BLK   4
#define BLKS_PER_ROW (NC / CH_PER_BLK)        // 64
#define K2_BLOCKS    (NTB * BLKS_PER_ROW)     // 1536
#define VF4_PER_BLK  (CH_PER_BLK * HW / 4)    // 4096
#define VF4_PER_THR  (VF4_PER_BLK / 64)       // 64

__global__ __launch_bounds__(64) void k_maskapply(const float* __restrict__ i0,
                                                  const float* __restrict__ i1,
                                                  const float* __restrict__ i2,
                                                  const float* __restrict__ imp,
                                                  vf4* __restrict__ out) {
  __shared__ unsigned mbits[HW / 32];          // 128 words = full row mask
  const int blk  = blockIdx.x;
  const int row  = blk >> 6;                   // 0..23 (t*8+b)
  const int cb   = blk & 63;                   // channel-chunk within row
  const int lane = threadIdx.x;                // 0..63, one wave

  // ---- select (R5 math, u[64] in registers under launch_bounds(64)) ------
  {
    const float* base = imp + (size_t)row * HW;
    unsigned u[64];
    const vf4* p = reinterpret_cast<const vf4*>(base + lane * 64);
#pragma unroll
    for (int j = 0; j < 16; ++j) {
      vf4 v = p[j];
      u[4 * j + 0] = __float_as_uint(v.x);
      u[4 * j + 1] = __float_as_uint(v.y);
      u[4 * j + 2] = __float_as_uint(v.z);
      u[4 * j + 3] = __float_as_uint(v.w);
    }
    unsigned mx = 0u, mn = 0xFFFFFFFFu;
#pragma unroll
    for (int j = 0; j < 64; ++j) {
      mx = (u[j] > mx) ? u[j] : mx;
      mn = (u[j] < mn) ? u[j] : mn;
    }
#pragma unroll
    for (int off = 32; off > 0; off >>= 1) {
      unsigned ox = (unsigned)__shfl_xor((int)mx, off, 64);
      unsigned on = (unsigned)__shfl_xor((int)mn, off, 64);
      mx = (ox > mx) ? ox : mx;
      mn = (on < mn) ? on : mn;
    }
    unsigned lo = mn, hi = mx + 1u;            // cnt_ge(lo)>=K, cnt_ge(hi)<K
    while (hi - lo > 1u) {
      unsigned mid = lo + ((hi - lo) >> 1);
      int c = 0;
#pragma unroll
      for (int j = 0; j < 64; ++j) c += (u[j] >= mid);
#pragma unroll
      for (int off = 32; off > 0; off >>= 1) c += __shfl_xor(c, off, 64);
      if (c >= TOPK) lo = mid; else hi = mid;  // c uniform across lanes
    }
    const unsigned thr = lo;
    int eq = 0, gt = 0;
#pragma unroll
    for (int j = 0; j < 64; ++j) {
      eq += (u[j] == thr);
      gt += (u[j] > thr);
    }
    int g_tot = gt;
#pragma unroll
    for (int off = 32; off > 0; off >>= 1) g_tot += __shfl_xor(g_tot, off, 64);
    int incl = eq;
#pragma unroll
    for (int off = 1; off < 64; off <<= 1) {
      int n = __shfl_up(incl, off, 64);
      if (lane >= off) incl += n;
    }
    int r = incl - eq;                         // starting tie-rank, lane order
    const int needed = TOPK - g_tot;
    unsigned w0 = 0u, w1 = 0u;
#pragma unroll
    for (int j = 0; j < 64; ++j) {             // same keep-decision as R5
      unsigned x = u[j];
      int e = (x == thr);
      unsigned keep = (x > thr || (e && r < needed)) ? 1u : 0u;
      if (j < 32) w0 |= keep << j; else w1 |= keep << (j - 32);
      r += e;
    }
    mbits[2 * lane]     = w0;                  // hw [lane*64,    lane*64+32)
    mbits[2 * lane + 1] = w1;                  // hw [lane*64+32, lane*64+64)
  }
  __syncthreads();                             // 1 wave: compiles to waitcnt

  // ---- apply: 4 channels of this row, 64 vf4/thread, 8 batches of 8 ------
  const int t = row >> 3;
  const vf4* src = (t == 0 ? (const vf4*)i0 : (t == 1 ? (const vf4*)i1 : (const vf4*)i2));
  const size_t src_base = ((size_t)(row & 7) * NC + (size_t)cb * CH_PER_BLK) * (HW / 4);
  vf4* obase = out + (size_t)row * NC * (HW / 4) + (size_t)cb * CH_PER_BLK * (HW / 4);
#pragma unroll
  for (int it = 0; it < VF4_PER_THR / 8; ++it) {
    int jj[8];
    vf4 a[8];
    unsigned nib[8];
#pragma unroll
    for (int q = 0; q < 8; ++q) {
      int j = lane + (it * 8 + q) * 64;        // 0..4095 vf4 within chunk
      jj[q] = j;
      a[q] = src[src_base + j];                // cached read (L3-resident)
      int h4 = j & 1023;                       // hw4 (chunk is channel-aligned)
      nib[q] = (mbits[h4 >> 3] >> ((h4 & 7) * 4)) & 15u;
    }
#pragma unroll
    for (int q = 0; q < 8; ++q) {
      vf4 r;
      r.x = (nib[q] & 1u) ? a[q].x : 0.f;
      r.y = (nib[q] & 2u) ? a[q].y : 0.f;
      r.z = (nib[q] & 4u) ? a[q].z : 0.f;
      r.w = (nib[q] & 8u) ? a[q].w : 0.f;
      __builtin_nontemporal_store(r, &obase[jj[q]]);
    }
  }
}

extern "C" void kernel_launch(void* const* d_in, const int* in_sizes, int n_in,
                              void* d_out, int out_size, void* d_ws, size_t ws_size,
                              hipStream_t stream) {
  const float* i0 = (const float*)d_in[0];
  const float* i1 = (const float*)d_in[1];
  const float* i2 = (const float*)d_in[2];
  float* imp = (float*)d_ws;   // 384 KB scratch (imp only; mask stays on-chip)

  k_imp<<<384, 256, 0, stream>>>(i0, i1, i2, imp);
  k_maskapply<<<K2_BLOCKS, 64, 0, stream>>>(i0, i1, i2, imp, (vf4*)d_out);
}